// Round 1
// baseline (243.366 us; speedup 1.0000x reference)
//
#include <hip/hip_runtime.h>
#include <hip/hip_bf16.h>

// SkipGramNS: out[i] = dot(cxt_weight[ctx_idx[i]], tgt_weight[tgt_idx[i]]), D=128.
// 32 lanes per pair; each lane loads one float4 from each row (32*16B = 512B = full row),
// computes a 4-element partial dot, then a 5-step shfl_xor butterfly reduces within the
// 32-lane group (masks 1..16 stay inside each 32-lane half of the 64-lane wave).

#define D 128

__global__ __launch_bounds__(256) void skipgram_dot_kernel(
    const int* __restrict__ ctx_idx,
    const int* __restrict__ tgt_idx,
    const float* __restrict__ cxt_w,
    const float* __restrict__ tgt_w,
    float* __restrict__ out,
    int n)
{
    const int lane = threadIdx.x & 31;                               // lane within 32-lane group
    const int pair = (int)((blockIdx.x * (unsigned)blockDim.x + threadIdx.x) >> 5);
    if (pair >= n) return;

    const int ci = ctx_idx[pair];   // same address for all 32 lanes -> broadcast
    const int ti = tgt_idx[pair];

    const float4* crow = reinterpret_cast<const float4*>(cxt_w + (size_t)ci * D);
    const float4* trow = reinterpret_cast<const float4*>(tgt_w + (size_t)ti * D);

    const float4 c = crow[lane];
    const float4 t = trow[lane];

    float p = c.x * t.x;
    p = fmaf(c.y, t.y, p);
    p = fmaf(c.z, t.z, p);
    p = fmaf(c.w, t.w, p);

    // Reduce across the 32-lane group (stays within half-wave on wave64).
    p += __shfl_xor(p, 16);
    p += __shfl_xor(p, 8);
    p += __shfl_xor(p, 4);
    p += __shfl_xor(p, 2);
    p += __shfl_xor(p, 1);

    if (lane == 0) out[pair] = p;
}

extern "C" void kernel_launch(void* const* d_in, const int* in_sizes, int n_in,
                              void* d_out, int out_size, void* d_ws, size_t ws_size,
                              hipStream_t stream) {
    const int*   ctx_idx = (const int*)d_in[0];
    const int*   tgt_idx = (const int*)d_in[1];
    const float* cxt_w   = (const float*)d_in[2];
    const float* tgt_w   = (const float*)d_in[3];
    float*       out     = (float*)d_out;

    const int n = in_sizes[0];                 // N pairs
    const int block = 256;                     // 8 pairs per block
    const int pairs_per_block = block / 32;
    const int grid = (n + pairs_per_block - 1) / pairs_per_block;

    skipgram_dot_kernel<<<grid, block, 0, stream>>>(ctx_idx, tgt_idx, cxt_w, tgt_w, out, n);
}

// Round 2
// 237.947 us; speedup vs baseline: 1.0228x; 1.0228x over previous
//
#include <hip/hip_runtime.h>
#include <hip/hip_bf16.h>

// SkipGramNS: out[i] = dot(cxt_weight[ctx_idx[i]], tgt_weight[tgt_idx[i]]), D=128.
// R1: 32-lane group handles 4 pairs. Two int4 broadcast index loads, then all
// 8 independent float4 row loads issued back-to-back (8 KB in flight per wave,
// 4x the R0 MLP) before the shfl reductions. Lane 0 stores 4 results as float4.

#define D 128

__global__ __launch_bounds__(256) void skipgram_dot_kernel(
    const int* __restrict__ ctx_idx,
    const int* __restrict__ tgt_idx,
    const float* __restrict__ cxt_w,
    const float* __restrict__ tgt_w,
    float* __restrict__ out,
    int n)
{
    const int lane = threadIdx.x & 31;
    const long long g = ((long long)blockIdx.x * blockDim.x + threadIdx.x) >> 5;
    const int p0 = (int)(g << 2);          // first of 4 pairs for this group
    if (p0 >= n) return;

    if (p0 + 4 <= n) {
        // Broadcast index loads (all lanes same address -> one line each).
        const int4 ci4 = *reinterpret_cast<const int4*>(ctx_idx + p0);
        const int4 ti4 = *reinterpret_cast<const int4*>(tgt_idx + p0);
        const int ci[4] = {ci4.x, ci4.y, ci4.z, ci4.w};
        const int ti[4] = {ti4.x, ti4.y, ti4.z, ti4.w};

        // Issue all 8 row loads before any use.
        float4 c[4], t[4];
        #pragma unroll
        for (int u = 0; u < 4; ++u) {
            c[u] = reinterpret_cast<const float4*>(cxt_w + (size_t)ci[u] * D)[lane];
            t[u] = reinterpret_cast<const float4*>(tgt_w + (size_t)ti[u] * D)[lane];
        }

        // 4 independent partial dots + butterflies (good VALU ILP).
        float p[4];
        #pragma unroll
        for (int u = 0; u < 4; ++u) {
            float s = c[u].x * t[u].x;
            s = fmaf(c[u].y, t[u].y, s);
            s = fmaf(c[u].z, t[u].z, s);
            s = fmaf(c[u].w, t[u].w, s);
            p[u] = s;
        }
        #pragma unroll
        for (int u = 0; u < 4; ++u) {
            p[u] += __shfl_xor(p[u], 16);
            p[u] += __shfl_xor(p[u], 8);
            p[u] += __shfl_xor(p[u], 4);
            p[u] += __shfl_xor(p[u], 2);
            p[u] += __shfl_xor(p[u], 1);
        }

        if (lane == 0) {
            *reinterpret_cast<float4*>(out + p0) = make_float4(p[0], p[1], p[2], p[3]);
        }
    } else {
        // Tail: scalar per-pair path.
        for (int u = 0; u < 4 && p0 + u < n; ++u) {
            const int pi = p0 + u;
            const int cidx = ctx_idx[pi];
            const int tidx = tgt_idx[pi];
            const float4 c = reinterpret_cast<const float4*>(cxt_w + (size_t)cidx * D)[lane];
            const float4 t = reinterpret_cast<const float4*>(tgt_w + (size_t)tidx * D)[lane];
            float s = c.x * t.x;
            s = fmaf(c.y, t.y, s);
            s = fmaf(c.z, t.z, s);
            s = fmaf(c.w, t.w, s);
            s += __shfl_xor(s, 16);
            s += __shfl_xor(s, 8);
            s += __shfl_xor(s, 4);
            s += __shfl_xor(s, 2);
            s += __shfl_xor(s, 1);
            if (lane == 0) out[pi] = s;
        }
    }
}

extern "C" void kernel_launch(void* const* d_in, const int* in_sizes, int n_in,
                              void* d_out, int out_size, void* d_ws, size_t ws_size,
                              hipStream_t stream) {
    const int*   ctx_idx = (const int*)d_in[0];
    const int*   tgt_idx = (const int*)d_in[1];
    const float* cxt_w   = (const float*)d_in[2];
    const float* tgt_w   = (const float*)d_in[3];
    float*       out     = (float*)d_out;

    const int n = in_sizes[0];                 // N pairs
    const int block = 256;                     // 8 groups * 4 pairs = 32 pairs/block
    const int pairs_per_block = (block / 32) * 4;
    const int grid = (n + pairs_per_block - 1) / pairs_per_block;

    skipgram_dot_kernel<<<grid, block, 0, stream>>>(ctx_idx, tgt_idx, cxt_w, tgt_w, out, n);
}

// Round 3
// 198.342 us; speedup vs baseline: 1.2270x; 1.1997x over previous
//
#include <hip/hip_runtime.h>
#include <hip/hip_bf16.h>
#include <hip/hip_fp16.h>

// SkipGramNS: out[i] = dot(cxt_weight[ctx[i]], tgt_weight[tgt[i]]), D=128.
// R2: gather path is fabric-bandwidth-bound (~7.2 TB/s on 1.02 GB of random
// 512B row reads; R1's 4x MLP moved nothing). Halve the bytes: convert both
// fp32 tables to fp16 in d_ws each call (51.2 MB total -> MALL-resident),
// then gather fp16 rows (256 B/row). 16-lane groups, 4 pairs/group, 16B loads.

#define D 128

typedef _Float16 half8_t __attribute__((ext_vector_type(8)));

// ---- Pass 1: fp32 -> fp16 table conversion (streaming) ----
__global__ __launch_bounds__(256) void convert_fp16_kernel(
    const float* __restrict__ cxt_w, const float* __restrict__ tgt_w,
    _Float16* __restrict__ cxt_h, _Float16* __restrict__ tgt_h,
    int elems_per_table)  // multiple of 8
{
    const int per_table_thr = elems_per_table >> 3;   // 8 floats per thread
    const int tid = blockIdx.x * blockDim.x + threadIdx.x;

    const float* src;
    _Float16* dst;
    int off;
    if (tid < per_table_thr) {
        src = cxt_w; dst = cxt_h; off = tid << 3;
    } else if (tid < 2 * per_table_thr) {
        src = tgt_w; dst = tgt_h; off = (tid - per_table_thr) << 3;
    } else {
        return;
    }

    const float4 a = *reinterpret_cast<const float4*>(src + off);
    const float4 b = *reinterpret_cast<const float4*>(src + off + 4);
    half8_t h;
    h[0] = (_Float16)a.x; h[1] = (_Float16)a.y;
    h[2] = (_Float16)a.z; h[3] = (_Float16)a.w;
    h[4] = (_Float16)b.x; h[5] = (_Float16)b.y;
    h[6] = (_Float16)b.z; h[7] = (_Float16)b.w;
    *reinterpret_cast<half8_t*>(dst + off) = h;
}

// ---- Pass 2: fp16 gather + dot. 16 lanes/pair (16 x 16B = 256B row), 4 pairs/group ----
__global__ __launch_bounds__(256) void gather_dot_h_kernel(
    const int* __restrict__ ctx_idx,
    const int* __restrict__ tgt_idx,
    const _Float16* __restrict__ cxt_h,
    const _Float16* __restrict__ tgt_h,
    float* __restrict__ out,
    int n)
{
    const int lane = threadIdx.x & 15;
    const long long g = ((long long)blockIdx.x * blockDim.x + threadIdx.x) >> 4;
    const int p0 = (int)(g << 2);
    if (p0 >= n) return;

    if (p0 + 4 <= n) {
        const int4 ci4 = *reinterpret_cast<const int4*>(ctx_idx + p0);
        const int4 ti4 = *reinterpret_cast<const int4*>(tgt_idx + p0);
        const int ci[4] = {ci4.x, ci4.y, ci4.z, ci4.w};
        const int ti[4] = {ti4.x, ti4.y, ti4.z, ti4.w};

        half8_t c[4], t[4];
        #pragma unroll
        for (int u = 0; u < 4; ++u) {
            c[u] = *reinterpret_cast<const half8_t*>(cxt_h + (size_t)ci[u] * D + lane * 8);
            t[u] = *reinterpret_cast<const half8_t*>(tgt_h + (size_t)ti[u] * D + lane * 8);
        }

        float p[4];
        #pragma unroll
        for (int u = 0; u < 4; ++u) {
            float s = 0.f;
            #pragma unroll
            for (int k = 0; k < 8; ++k)
                s = fmaf((float)c[u][k], (float)t[u][k], s);
            p[u] = s;
        }
        #pragma unroll
        for (int u = 0; u < 4; ++u) {
            p[u] += __shfl_xor(p[u], 8);
            p[u] += __shfl_xor(p[u], 4);
            p[u] += __shfl_xor(p[u], 2);
            p[u] += __shfl_xor(p[u], 1);
        }
        if (lane == 0)
            *reinterpret_cast<float4*>(out + p0) = make_float4(p[0], p[1], p[2], p[3]);
    } else {
        for (int u = 0; u < 4 && p0 + u < n; ++u) {
            const int pi = p0 + u;
            const int cidx = ctx_idx[pi];
            const int tidx = tgt_idx[pi];
            const half8_t c = *reinterpret_cast<const half8_t*>(cxt_h + (size_t)cidx * D + lane * 8);
            const half8_t t = *reinterpret_cast<const half8_t*>(tgt_h + (size_t)tidx * D + lane * 8);
            float s = 0.f;
            #pragma unroll
            for (int k = 0; k < 8; ++k)
                s = fmaf((float)c[k], (float)t[k], s);
            s += __shfl_xor(s, 8);
            s += __shfl_xor(s, 4);
            s += __shfl_xor(s, 2);
            s += __shfl_xor(s, 1);
            if (lane == 0) out[pi] = s;
        }
    }
}

// ---- Fallback (ws too small): R1 fp32 path ----
__global__ __launch_bounds__(256) void gather_dot_f32_kernel(
    const int* __restrict__ ctx_idx, const int* __restrict__ tgt_idx,
    const float* __restrict__ cxt_w, const float* __restrict__ tgt_w,
    float* __restrict__ out, int n)
{
    const int lane = threadIdx.x & 31;
    const long long g = ((long long)blockIdx.x * blockDim.x + threadIdx.x) >> 5;
    const int pair = (int)g;
    if (pair >= n) return;
    const int ci = ctx_idx[pair];
    const int ti = tgt_idx[pair];
    const float4 c = reinterpret_cast<const float4*>(cxt_w + (size_t)ci * D)[lane];
    const float4 t = reinterpret_cast<const float4*>(tgt_w + (size_t)ti * D)[lane];
    float s = c.x * t.x;
    s = fmaf(c.y, t.y, s);
    s = fmaf(c.z, t.z, s);
    s = fmaf(c.w, t.w, s);
    s += __shfl_xor(s, 16);
    s += __shfl_xor(s, 8);
    s += __shfl_xor(s, 4);
    s += __shfl_xor(s, 2);
    s += __shfl_xor(s, 1);
    if (lane == 0) out[pair] = s;
}

extern "C" void kernel_launch(void* const* d_in, const int* in_sizes, int n_in,
                              void* d_out, int out_size, void* d_ws, size_t ws_size,
                              hipStream_t stream) {
    const int*   ctx_idx = (const int*)d_in[0];
    const int*   tgt_idx = (const int*)d_in[1];
    const float* cxt_w   = (const float*)d_in[2];
    const float* tgt_w   = (const float*)d_in[3];
    float*       out     = (float*)d_out;

    const int n = in_sizes[0];            // N pairs
    const int elems = in_sizes[2];        // V*D per table
    const size_t need = (size_t)elems * 2 * sizeof(_Float16);

    if (ws_size >= need) {
        _Float16* cxt_h = (_Float16*)d_ws;
        _Float16* tgt_h = cxt_h + elems;

        // Pass 1: convert both tables (one thread per 8 floats, both tables).
        const int conv_threads = (elems >> 3) * 2;
        const int conv_grid = (conv_threads + 255) / 256;
        convert_fp16_kernel<<<conv_grid, 256, 0, stream>>>(
            cxt_w, tgt_w, cxt_h, tgt_h, elems);

        // Pass 2: gather+dot. 16 lanes/pair, 4 pairs per 16-lane group.
        const int pairs_per_block = (256 / 16) * 4;   // 64
        const int grid = (n + pairs_per_block - 1) / pairs_per_block;
        gather_dot_h_kernel<<<grid, 256, 0, stream>>>(
            ctx_idx, tgt_idx, cxt_h, tgt_h, out, n);
    } else {
        const int grid = (n + 7) / 8;   // 8 pairs per 256-thread block
        gather_dot_f32_kernel<<<grid, 256, 0, stream>>>(
            ctx_idx, tgt_idx, cxt_w, tgt_w, out, n);
    }
}